// Round 2
// baseline (244.043 us; speedup 1.0000x reference)
//
#include <hip/hip_runtime.h>
#include <hip/hip_bf16.h>

// ---------------------------------------------------------------------------
// AMM chain on MI355X: all GEMMs as NT fp16-MFMA (f32 accum), fused epilogues.
// M=512 fixed; tiles 64x64, BK=64, 4 waves/block, XOR-swizzled LDS staging via
// global_load_lds(16B). ISTA iteration 1 fused (z1 = soft(z0,1), exact since
// val_enc^T val_enc = I). Output written as FLOAT32 (reference output dtype).
// Workspace use: ~40 MB.
// ---------------------------------------------------------------------------

typedef _Float16 f16x8 __attribute__((ext_vector_type(8)));
typedef _Float16 f16x4 __attribute__((ext_vector_type(4)));
typedef float f32x4 __attribute__((ext_vector_type(4)));

enum { EPI_QB, EPI_SCALE, EPI_F32H, EPI_SOFT, EPI_RESID, EPI_ZUP, EPI_FINAL };

typedef const __attribute__((address_space(1))) void* gas_ptr;
typedef __attribute__((address_space(3))) void* las_ptr;

__device__ __forceinline__ void gload16(const void* g, void* l) {
  __builtin_amdgcn_global_load_lds((gas_ptr)g, (las_ptr)l, 16, 0, 0);
}

__device__ __forceinline__ float softt(float t) {
  float s = fabsf(t) - 1.0f;
  s = s > 0.0f ? s : 0.0f;
  return copysignf(s, t);
}

// ---------------------------------------------------------------------------
// f32 -> f16 plain convert (vectorized x4)
// ---------------------------------------------------------------------------
__global__ __launch_bounds__(256) void conv_h(const float4* __restrict__ in,
                                              f16x4* __restrict__ out, int n4) {
  int i = blockIdx.x * 256 + threadIdx.x;
  if (i >= n4) return;
  float4 v = in[i];
  f16x4 h = {(_Float16)v.x, (_Float16)v.y, (_Float16)v.z, (_Float16)v.w};
  out[i] = h;
}

// ---------------------------------------------------------------------------
// f32 (R,C) -> f16 (C,R) transposing convert. 32x32 LDS tile, block (32,8).
// ---------------------------------------------------------------------------
__global__ __launch_bounds__(256) void convT_h(const float* __restrict__ in,
                                               _Float16* __restrict__ out,
                                               int R, int C) {
  __shared__ float t[32][33];
  int tx = threadIdx.x, ty = threadIdx.y;
  int c0 = blockIdx.x * 32, r0 = blockIdx.y * 32;
#pragma unroll
  for (int i = 0; i < 32; i += 8)
    t[ty + i][tx] = in[(size_t)(r0 + ty + i) * C + c0 + tx];
  __syncthreads();
#pragma unroll
  for (int i = 0; i < 32; i += 8)
    out[(size_t)(c0 + ty + i) * R + r0 + tx] = (_Float16)t[tx][ty + i];
}

// ---------------------------------------------------------------------------
// NT GEMM: C[m,n] = sum_k A[m,k]*B[n,k]; A (512,K) rm, B (N,K) rm, fp16 in,
// f32 accum. 64x64 tile, BK=64, 256 thr = 4 waves (2x2 of 32x32 subtiles),
// per wave 2x2 fragments of 16x16x32 MFMA.
// LDS layout: tile row r, k-chunk g (8 halfs) stored at halfs r*64 + (g^(r&7))*8
// (XOR swizzle; staged linearly by global_load_lds with pre-swizzled source).
// ---------------------------------------------------------------------------
template <int EPI>
__global__ __launch_bounds__(256) void gemm64(
    const _Float16* __restrict__ A, const _Float16* __restrict__ B,
    const int N, const int K, const float* __restrict__ scale,
    const float* __restrict__ caux, float* __restrict__ outf,
    _Float16* __restrict__ outh, _Float16* __restrict__ outh2) {
  __shared__ __align__(16) _Float16 As[4096];
  __shared__ __align__(16) _Float16 Bs[4096];
  const int tid = threadIdx.x;
  const int lane = tid & 63;
  const int w = tid >> 6;
  const int wr = w >> 1;
  const int wc = w & 1;
  const int brow = blockIdx.y << 6;
  const int bcol = blockIdx.x << 6;

  // staging map: segment s = w*2+j covers LDS bytes [s*1024, s*1024+1024),
  // lane writes 16B at s*1024 + lane*16 -> row = s*8 + (lane>>3), chunk = lane&7.
  // source chunk g = (lane&7) ^ (row&7) = (lane&7) ^ ((lane>>3)&7).
  const int srow = lane >> 3;
  const int scol = ((lane & 7) ^ srow) << 3;

  const _Float16* apg = A + (size_t)(brow + (w << 4) + srow) * K + scol;
  const _Float16* bpg = B + (size_t)(bcol + (w << 4) + srow) * K + scol;
  _Float16* apl = As + (w << 1) * 512;
  _Float16* bpl = Bs + (w << 1) * 512;

  const int a15 = lane & 15;
  const int hi = lane >> 4;

  f32x4 acc[2][2] = {};

  const int nK = K >> 6;
  for (int kt = 0; kt < nK; ++kt) {
    gload16(apg, apl);
    gload16(apg + (size_t)8 * K, apl + 512);
    gload16(bpg, bpl);
    gload16(bpg + (size_t)8 * K, bpl + 512);
    apg += 64;
    bpg += 64;
    __syncthreads();
#pragma unroll
    for (int kk = 0; kk < 2; ++kk) {
      f16x8 av[2], bv[2];
#pragma unroll
      for (int mi = 0; mi < 2; ++mi) {
        int r = (wr << 5) + (mi << 4) + a15;
        int ch = ((kk << 2) + hi) ^ (r & 7);
        av[mi] = *(const f16x8*)(As + (r << 6) + (ch << 3));
      }
#pragma unroll
      for (int ni = 0; ni < 2; ++ni) {
        int r = (wc << 5) + (ni << 4) + a15;
        int ch = ((kk << 2) + hi) ^ (r & 7);
        bv[ni] = *(const f16x8*)(Bs + (r << 6) + (ch << 3));
      }
#pragma unroll
      for (int mi = 0; mi < 2; ++mi)
#pragma unroll
        for (int ni = 0; ni < 2; ++ni)
          acc[mi][ni] = __builtin_amdgcn_mfma_f32_16x16x32_f16(
              av[mi], bv[ni], acc[mi][ni], 0, 0, 0);
    }
    __syncthreads();
  }

  // epilogue: D layout col = lane&15, row = (lane>>4)*4 + r  [m89-verified]
#pragma unroll
  for (int mi = 0; mi < 2; ++mi) {
#pragma unroll
    for (int ni = 0; ni < 2; ++ni) {
#pragma unroll
      for (int r = 0; r < 4; ++r) {
        const int row = brow + (wr << 5) + (mi << 4) + (hi << 2) + r;
        const int col = bcol + (wc << 5) + (ni << 4) + a15;
        const float v = acc[mi][ni][r];
        const size_t idx = (size_t)row * N + col;
        if constexpr (EPI == EPI_QB) {
          // fused x@[key_enc^T ; keys_t1^T]: first 1024 cols -> q, rest -> betas2
          if (col < 1024)
            outh[(size_t)row * 1024 + col] = (_Float16)v;
          else
            outh2[(size_t)row * 1024 + (col - 1024)] =
                (_Float16)(v * scale[col - 1024]);
        } else if constexpr (EPI == EPI_SCALE) {
          outh[idx] = (_Float16)(v * scale[col]);
        } else if constexpr (EPI == EPI_F32H) {
          outf[idx] = v;
          outh[idx] = (_Float16)v;
        } else if constexpr (EPI == EPI_SOFT) {
          float z = softt(v);  // fused ISTA iteration 1
          outf[idx] = z;
          outh[idx] = (_Float16)z;
        } else if constexpr (EPI == EPI_RESID) {
          outh[idx] = (_Float16)(caux[idx] - v);  // r = yb - w
        } else if constexpr (EPI == EPI_ZUP) {
          float z = softt(caux[idx] + v);  // z = soft(z + r@Ve^T, 1)
          outf[idx] = z;
          outh[idx] = (_Float16)z;
        } else {  // EPI_FINAL: y = z + betas2@V1^T  -> f32 output
          outf[idx] = caux[idx] + v;
        }
      }
    }
  }
}

// ---------------------------------------------------------------------------
extern "C" void kernel_launch(void* const* d_in, const int* in_sizes, int n_in,
                              void* d_out, int out_size, void* d_ws,
                              size_t ws_size, hipStream_t stream) {
  const float* x = (const float*)d_in[0];          // (512,2048)
  const float* key_enc = (const float*)d_in[1];    // (2048,1024)
  const float* val_enc = (const float*)d_in[2];    // (2048,1024)
  const float* keys_t0 = (const float*)d_in[3];    // (1024,1024)
  const float* vals_t0 = (const float*)d_in[4];    // (1024,1024)
  const float* scales_t0 = (const float*)d_in[5];  // (1024,1)
  const float* keys_t1 = (const float*)d_in[6];    // (2048,1024)
  const float* vals_t1 = (const float*)d_in[7];    // (2048,1024)
  const float* scales_t1 = (const float*)d_in[8];  // (1024,1)

  // workspace carve-up (~40 MB)
  _Float16* x_h = (_Float16*)d_ws;          // 512*2048
  _Float16* Bcat = x_h + 1048576;           // 2048*2048 [key_enc^T ; keys_t1^T]
  _Float16* kt0_h = Bcat + 4194304;         // 1024*1024
  _Float16* vt0_hT = kt0_h + 1048576;       // 1024*1024 (vals_t0^T)
  _Float16* ve_h = vt0_hT + 1048576;        // 2048*1024 (val_enc natural)
  _Float16* ve_hT = ve_h + 2097152;         // 1024*2048 (val_enc^T)
  _Float16* vt1_h = ve_hT + 2097152;        // 2048*1024
  _Float16* q_h = vt1_h + 2097152;          // 512*1024
  _Float16* be_h = q_h + 524288;            // 512*1024
  _Float16* be2_h = be_h + 524288;          // 512*1024
  _Float16* yb_h = be2_h + 524288;          // 512*1024
  _Float16* r_h = yb_h + 524288;            // 512*1024
  _Float16* z_h = r_h + 524288;             // 512*2048
  float* yb_f = (float*)(z_h + 1048576);    // 512*1024 f32
  float* z_f = yb_f + 524288;               // 512*2048 f32

  dim3 tb(32, 8);
  // conversions (pre-transposed so every GEMM is NT)
  conv_h<<<1024, 256, 0, stream>>>((const float4*)x, (f16x4*)x_h, 262144);
  convT_h<<<dim3(32, 64), tb, 0, stream>>>(key_enc, Bcat, 2048, 1024);
  convT_h<<<dim3(32, 64), tb, 0, stream>>>(keys_t1, Bcat + 2097152, 2048, 1024);
  conv_h<<<1024, 256, 0, stream>>>((const float4*)keys_t0, (f16x4*)kt0_h, 262144);
  convT_h<<<dim3(32, 32), tb, 0, stream>>>(vals_t0, vt0_hT, 1024, 1024);
  conv_h<<<2048, 256, 0, stream>>>((const float4*)val_enc, (f16x4*)ve_h, 524288);
  convT_h<<<dim3(32, 64), tb, 0, stream>>>(val_enc, ve_hT, 2048, 1024);
  conv_h<<<2048, 256, 0, stream>>>((const float4*)vals_t1, (f16x4*)vt1_h, 524288);

  // chain (all NT, M=512)
  // 1) q | betas2 = x @ [Ke^T;K1^T]  (N=2048,K=2048)
  gemm64<EPI_QB><<<dim3(32, 8), 256, 0, stream>>>(
      x_h, Bcat, 2048, 2048, scales_t1, nullptr, nullptr, q_h, be2_h);
  // 2) betas = (q @ K0^T) * s0       (N=1024,K=1024)
  gemm64<EPI_SCALE><<<dim3(16, 8), 256, 0, stream>>>(
      q_h, kt0_h, 1024, 1024, scales_t0, nullptr, nullptr, be_h, nullptr);
  // 3) yb = betas @ V0               (N=1024,K=1024)
  gemm64<EPI_F32H><<<dim3(16, 8), 256, 0, stream>>>(
      be_h, vt0_hT, 1024, 1024, nullptr, nullptr, yb_f, yb_h, nullptr);
  // 4) z = soft(yb @ Ve^T, 1)        (N=2048,K=1024)  [ISTA iter 1 fused]
  gemm64<EPI_SOFT><<<dim3(32, 8), 256, 0, stream>>>(
      yb_h, ve_h, 2048, 1024, nullptr, nullptr, z_f, z_h, nullptr);
  // 5) ISTA iterations 2..5
  for (int it = 0; it < 4; ++it) {
    gemm64<EPI_RESID><<<dim3(16, 8), 256, 0, stream>>>(
        z_h, ve_hT, 1024, 2048, nullptr, yb_f, nullptr, r_h, nullptr);
    gemm64<EPI_ZUP><<<dim3(32, 8), 256, 0, stream>>>(
        r_h, ve_h, 2048, 1024, nullptr, z_f, z_f, z_h, nullptr);
  }
  // 6) y = z + betas2 @ V1^T         (N=2048,K=1024) -> f32 out
  gemm64<EPI_FINAL><<<dim3(32, 8), 256, 0, stream>>>(
      be2_h, vt1_h, 2048, 1024, nullptr, z_f, (float*)d_out, nullptr, nullptr);
}

// Round 3
// 180.989 us; speedup vs baseline: 1.3484x; 1.3484x over previous
//
#include <hip/hip_runtime.h>

// ---------------------------------------------------------------------------
// AMM chain, round 3: projector-folded ISTA + 8-wave K-split GEMM + 2-phase
// double-buffered pipeline.
//   chain: C1 [q|betas2] -> C2 z0=q@W0'(soft) -> 4x z=soft(z0+z@Q) -> final
//   pre:   W0 = K0^T s0 V0 ; W0'^T = Ve@W0^T ; Q = I - Ve Ve^T (off-diag f16,
//          diag kept exact in f32 vector dg, applied in epilogue)
// All GEMMs NT fp16-MFMA f32-accum, 64x64 tile, BK=64, 512 thr (2x2x2 waves),
// XOR-swizzled LDS staging via global_load_lds(16B). Workspace: 36 MB.
// ---------------------------------------------------------------------------

typedef _Float16 f16x8 __attribute__((ext_vector_type(8)));
typedef _Float16 f16x4 __attribute__((ext_vector_type(4)));
typedef float f32x4 __attribute__((ext_vector_type(4)));

enum { EPI_H, EPI_QOFF, EPI_SPLIT, EPI_SOFT, EPI_ZQ, EPI_FINAL };

typedef const __attribute__((address_space(1))) void* gas_ptr;
typedef __attribute__((address_space(3))) void* las_ptr;

__device__ __forceinline__ void gload16(const void* g, void* l) {
  __builtin_amdgcn_global_load_lds((gas_ptr)g, (las_ptr)l, 16, 0, 0);
}

__device__ __forceinline__ float softt(float t) {
  float s = fabsf(t) - 1.0f;
  s = s > 0.0f ? s : 0.0f;
  return copysignf(s, t);
}

// ---------------------------------------------------------------------------
// fused plain f32->f16 convert over 3 tensors (grid-stride, float4 loads)
// ---------------------------------------------------------------------------
__global__ __launch_bounds__(256) void convP(
    const float4* __restrict__ sa, f16x4* __restrict__ da, int na,
    const float4* __restrict__ sb, f16x4* __restrict__ db, int nb,
    const float4* __restrict__ sc, f16x4* __restrict__ dc, int nc) {
  int total = na + nb + nc;
  for (int i = blockIdx.x * 256 + threadIdx.x; i < total;
       i += gridDim.x * 256) {
    const float4* s;
    f16x4* d;
    int j = i;
    if (j < na) {
      s = sa; d = da;
    } else if ((j -= na) < nb) {
      s = sb; d = db;
    } else {
      j -= nb; s = sc; d = dc;
    }
    float4 v = s[j];
    f16x4 h = {(_Float16)v.x, (_Float16)v.y, (_Float16)v.z, (_Float16)v.w};
    d[j] = h;
  }
}

// ---------------------------------------------------------------------------
// fused transposing f32->f16 convert, 4 slices via blockIdx.z, optional scale
// mode: 0 none, 1 scale by source-col (s[c]), 2 scale by source-row (s[r])
// out is (C,R): out[c][r] = in[r][c] * scale
// ---------------------------------------------------------------------------
__global__ __launch_bounds__(256) void convT4(
    const float* __restrict__ e0, const float* __restrict__ e1,
    const float* __restrict__ e2, const float* __restrict__ e3,
    _Float16* __restrict__ o0, _Float16* __restrict__ o1,
    _Float16* __restrict__ o2, _Float16* __restrict__ o3,
    const float* __restrict__ s1, const float* __restrict__ s2) {
  const int z = blockIdx.z;
  const float* in = z == 0 ? e0 : z == 1 ? e1 : z == 2 ? e2 : e3;
  _Float16* out = z == 0 ? o0 : z == 1 ? o1 : z == 2 ? o2 : o3;
  const int R = (z < 2) ? 2048 : 1024;
  const int C = 1024;
  const int mode = z == 1 ? 1 : z == 2 ? 2 : 0;
  const float* sv = z == 1 ? s1 : s2;
  __shared__ float t[32][33];
  const int tx = threadIdx.x, ty = threadIdx.y;
  const int c0 = blockIdx.x * 32, r0 = blockIdx.y * 32;
  if (r0 >= R) return;  // uniform per block
#pragma unroll
  for (int i = 0; i < 32; i += 8)
    t[ty + i][tx] = in[(size_t)(r0 + ty + i) * C + c0 + tx];
  __syncthreads();
#pragma unroll
  for (int i = 0; i < 32; i += 8) {
    float v = t[tx][ty + i];
    if (mode == 1) v *= sv[c0 + ty + i];
    if (mode == 2) v *= sv[r0 + tx];
    out[(size_t)(c0 + ty + i) * R + r0 + tx] = (_Float16)v;
  }
}

// ---------------------------------------------------------------------------
// NT GEMM: C[m,n] = sum_k A[m,k]*B[n,k], fp16 in, f32 accum.
// 64x64 tile, BK=64, 512 thr = 8 waves in 2x2x2 (M x N x Ksplit) grid,
// wave tile 32x32 (2x2 frags of 16x16x32 MFMA), double-buffered LDS with
// stage-ahead (one barrier per K-step), end-of-loop cross-K LDS reduction.
// LDS swizzle: row r, chunk c (8 halfs) at r*64 + ((c ^ (r&7))*8).
// ---------------------------------------------------------------------------
template <int EPI>
__global__ __launch_bounds__(512) void gemmk(
    const _Float16* __restrict__ A, const _Float16* __restrict__ B,
    const int N, const int K, const float* caux, const float* caux2,
    const float* dgv, float* dgout, float* outf, float* outf2,
    _Float16* __restrict__ outh, _Float16* __restrict__ outh2) {
  __shared__ __align__(16) _Float16 sm[16384];  // As[2][4096] | Bs[2][4096]
  const int tid = threadIdx.x;
  const int lane = tid & 63;
  const int w = tid >> 6;        // 0..7
  const int wr = (w >> 1) & 1;   // M half
  const int wc = w & 1;          // N half
  const int wk = w >> 2;         // K half within BK
  const int brow = blockIdx.y << 6;
  const int bcol = blockIdx.x << 6;

  // staging: wave w stages A rows [8w,8w+8) and B rows [8w,8w+8)
  const int srow = lane >> 3;
  const int scol = ((lane & 7) ^ srow) << 3;  // pre-swizzled source chunk
  const int a15 = lane & 15;
  const int hi = lane >> 4;
  const int l7 = lane & 7;

  const _Float16* apg = A + (size_t)(brow + (w << 3) + srow) * K + scol;
  const _Float16* bpg = B + (size_t)(bcol + (w << 3) + srow) * K + scol;

  f32x4 acc[2][2] = {};
  const int nK = K >> 6;

  // stage tile 0 -> buf 0
  gload16(apg, sm + (w << 9));
  gload16(bpg, sm + 8192 + (w << 9));
  __syncthreads();

  // fragment read offsets (halfs), buf-relative; row&7 == lane&7 here
  int raddr[2], baddr[2];
#pragma unroll
  for (int mi = 0; mi < 2; ++mi) {
    int ra = (wr << 5) + (mi << 4) + a15;
    int ca = ((wk << 2) + hi) ^ l7;
    raddr[mi] = ra * 64 + (ca << 3);
  }
#pragma unroll
  for (int ni = 0; ni < 2; ++ni) {
    int rb = (wc << 5) + (ni << 4) + a15;
    int cb = ((wk << 2) + hi) ^ l7;
    baddr[ni] = rb * 64 + (cb << 3);
  }

  for (int kt = 0; kt < nK; ++kt) {
    if (kt + 1 < nK) {  // stage next tile into other buf (issue-early)
      const int nb = (kt + 1) & 1;
      gload16(apg + ((size_t)(kt + 1) << 6), sm + (nb << 12) + (w << 9));
      gload16(bpg + ((size_t)(kt + 1) << 6),
              sm + 8192 + (nb << 12) + (w << 9));
    }
    const _Float16* Ab = sm + ((kt & 1) << 12);
    const _Float16* Bb = sm + 8192 + ((kt & 1) << 12);
    f16x8 av[2], bv[2];
    av[0] = *(const f16x8*)(Ab + raddr[0]);
    av[1] = *(const f16x8*)(Ab + raddr[1]);
    bv[0] = *(const f16x8*)(Bb + baddr[0]);
    bv[1] = *(const f16x8*)(Bb + baddr[1]);
#pragma unroll
    for (int mi = 0; mi < 2; ++mi)
#pragma unroll
      for (int ni = 0; ni < 2; ++ni)
        acc[mi][ni] = __builtin_amdgcn_mfma_f32_16x16x32_f16(
            av[mi], bv[ni], acc[mi][ni], 0, 0, 0);
    __syncthreads();  // next buf staged + everyone done with cur buf
  }

  // cross-K reduction through LDS scratch (16 KB)
  float* scr = (float*)sm;
  const int rbase = ((w & 3) * 64 + lane) * 16;
  if (wk == 1) {
#pragma unroll
    for (int mi = 0; mi < 2; ++mi)
#pragma unroll
      for (int ni = 0; ni < 2; ++ni)
        *(f32x4*)(scr + rbase + ((mi * 2 + ni) << 2)) = acc[mi][ni];
  }
  __syncthreads();
  if (wk == 1) return;
#pragma unroll
  for (int mi = 0; mi < 2; ++mi)
#pragma unroll
    for (int ni = 0; ni < 2; ++ni)
      acc[mi][ni] += *(const f32x4*)(scr + rbase + ((mi * 2 + ni) << 2));

  // epilogue: D layout col = lane&15, row = (lane>>4)*4 + r  [m89-verified]
#pragma unroll
  for (int mi = 0; mi < 2; ++mi) {
#pragma unroll
    for (int ni = 0; ni < 2; ++ni) {
#pragma unroll
      for (int r = 0; r < 4; ++r) {
        const int row = brow + (wr << 5) + (mi << 4) + (hi << 2) + r;
        const int col = bcol + (wc << 5) + (ni << 4) + a15;
        const float v = acc[mi][ni][r];
        const size_t idx = (size_t)row * N + col;
        if constexpr (EPI == EPI_H) {
          outh[idx] = (_Float16)v;
        } else if constexpr (EPI == EPI_QOFF) {
          // Q = I - Ve Ve^T: off-diag -> f16, diag -> exact f32 vector
          if (row == col) {
            dgout[row] = 1.0f - v;
            outh[idx] = (_Float16)0.0f;
          } else {
            outh[idx] = (_Float16)(-v);
          }
        } else if constexpr (EPI == EPI_SPLIT) {
          if (col < 1024)
            outh[(size_t)row * 1024 + col] = (_Float16)v;
          else
            outh2[(size_t)row * 1024 + (col - 1024)] = (_Float16)v;
        } else if constexpr (EPI == EPI_SOFT) {
          outf[idx] = v;  // z0 (f32, feeds all ZQ epilogues)
          float s = softt(v);
          outf2[idx] = s;  // z1 f32
          outh[idx] = (_Float16)s;
        } else if constexpr (EPI == EPI_ZQ) {
          // z_new = soft(z0 + dg[col]*z_prev + z_prev@Qoff, 1)
          float t = caux[idx] + dgv[col] * caux2[idx] + v;
          float s = softt(t);
          outf[idx] = s;  // aliases caux2 (read-before-write, same thread)
          outh[idx] = (_Float16)s;
        } else {  // EPI_FINAL: y = z + betas2@V1^T -> f32 d_out
          outf[idx] = caux[idx] + v;
        }
      }
    }
  }
}

// ---------------------------------------------------------------------------
extern "C" void kernel_launch(void* const* d_in, const int* in_sizes, int n_in,
                              void* d_out, int out_size, void* d_ws,
                              size_t ws_size, hipStream_t stream) {
  const float* x = (const float*)d_in[0];          // (512,2048)
  const float* key_enc = (const float*)d_in[1];    // (2048,1024)
  const float* val_enc = (const float*)d_in[2];    // (2048,1024)
  const float* keys_t0 = (const float*)d_in[3];    // (1024,1024)
  const float* vals_t0 = (const float*)d_in[4];    // (1024,1024)
  const float* scales_t0 = (const float*)d_in[5];  // (1024,)
  const float* keys_t1 = (const float*)d_in[6];    // (2048,1024)
  const float* vals_t1 = (const float*)d_in[7];    // (2048,1024)
  const float* scales_t1 = (const float*)d_in[8];  // (1024,)

  // workspace carve-up (36 MB total, with lifetime-based overlays)
  _Float16* wsh = (_Float16*)d_ws;
  _Float16* ve_h = wsh;                    // 2,097,152  (val_enc f16)
  _Float16* vt1_h = wsh + 2097152;         // 2,097,152  (vals_t1 f16)
  _Float16* w0pT = wsh + 4194304;          // 2,097,152  (W0'^T = Ve@W0^T)
  _Float16* Bcat = wsh + 6291456;          // 4,194,304  [Ke^T ; K1^T*s1]
  _Float16* qoff = Bcat;                   //   overlay: Q off-diag (after C1)
  _Float16* x_h = wsh + 10485760;          // 1,048,576
  float* dg = (float*)x_h;                 //   overlay: Q diagonal (after C1)
  _Float16* kt0s = wsh + 11534336;         // 1,048,576  (K0^T * s0)
  _Float16* zh_A = kt0s;                   //   overlay after W0
  _Float16* vt0T = wsh + 12582912;         // 1,048,576  (vals_t0^T)
  _Float16* zh_B = vt0T;                   //   overlay after W0
  _Float16* w0_h = wsh + 13631488;         // 1,048,576  (W0)
  _Float16* q_h = w0_h;                    //   overlay after w0pT
  _Float16* be2_h = w0_h + 524288;
  float* z0_f = (float*)(wsh + 14680064);  // 1,048,576 f32
  float* z_f = z0_f + 1048576;             // 1,048,576 f32  -> end @ 36 MB

  // 1-2) conversions
  convP<<<1280, 256, 0, stream>>>(
      (const float4*)x, (f16x4*)x_h, 262144,
      (const float4*)val_enc, (f16x4*)ve_h, 524288,
      (const float4*)vals_t1, (f16x4*)vt1_h, 524288);
  convT4<<<dim3(32, 64, 4), dim3(32, 8), 0, stream>>>(
      key_enc, keys_t1, keys_t0, vals_t0, Bcat, Bcat + 2097152, kt0s, vt0T,
      scales_t1, scales_t0);

  // 3) W0 = (K0^T s0) @ V0 : M=1024 N=1024 K=1024
  gemmk<EPI_H><<<dim3(16, 16), 512, 0, stream>>>(
      kt0s, vt0T, 1024, 1024, nullptr, nullptr, nullptr, nullptr, nullptr,
      nullptr, w0_h, nullptr);
  // 4) W0'^T = Ve @ W0^T : M=2048 N=1024 K=1024
  gemmk<EPI_H><<<dim3(16, 32), 512, 0, stream>>>(
      ve_h, w0_h, 1024, 1024, nullptr, nullptr, nullptr, nullptr, nullptr,
      nullptr, w0pT, nullptr);
  // 5) C1: [q | betas2] = x @ [Ke^T ; K1^T*s1] : M=512 N=2048 K=2048
  gemmk<EPI_SPLIT><<<dim3(32, 8), 512, 0, stream>>>(
      x_h, Bcat, 2048, 2048, nullptr, nullptr, nullptr, nullptr, nullptr,
      nullptr, q_h, be2_h);
  // 6) Q = I - Ve@Ve^T : M=2048 N=2048 K=1024 -> qoff (overlays Bcat) + dg
  gemmk<EPI_QOFF><<<dim3(32, 32), 512, 0, stream>>>(
      ve_h, ve_h, 2048, 1024, nullptr, nullptr, nullptr, dg, nullptr, nullptr,
      qoff, nullptr);
  // 7) C2: z0 = q @ W0' (soft fused -> z1) : M=512 N=2048 K=1024
  gemmk<EPI_SOFT><<<dim3(32, 8), 512, 0, stream>>>(
      q_h, w0pT, 2048, 1024, nullptr, nullptr, nullptr, nullptr, z0_f, z_f,
      zh_A, nullptr);
  // 8-11) ISTA iters 2..5: z = soft(z0 + z@Q) : M=512 N=2048 K=2048
  gemmk<EPI_ZQ><<<dim3(32, 8), 512, 0, stream>>>(
      zh_A, qoff, 2048, 2048, z0_f, z_f, dg, nullptr, z_f, nullptr, zh_B,
      nullptr);
  gemmk<EPI_ZQ><<<dim3(32, 8), 512, 0, stream>>>(
      zh_B, qoff, 2048, 2048, z0_f, z_f, dg, nullptr, z_f, nullptr, zh_A,
      nullptr);
  gemmk<EPI_ZQ><<<dim3(32, 8), 512, 0, stream>>>(
      zh_A, qoff, 2048, 2048, z0_f, z_f, dg, nullptr, z_f, nullptr, zh_B,
      nullptr);
  gemmk<EPI_ZQ><<<dim3(32, 8), 512, 0, stream>>>(
      zh_B, qoff, 2048, 2048, z0_f, z_f, dg, nullptr, z_f, nullptr, zh_A,
      nullptr);
  // 12) final: y = z + betas2 @ V1^T : M=512 N=2048 K=1024 -> f32 d_out
  gemmk<EPI_FINAL><<<dim3(32, 8), 512, 0, stream>>>(
      be2_h, vt1_h, 2048, 1024, z_f, nullptr, nullptr, nullptr, (float*)d_out,
      nullptr, nullptr, nullptr);
}

// Round 4
// 127.965 us; speedup vs baseline: 1.9071x; 1.4144x over previous
//
#include <hip/hip_runtime.h>

// ---------------------------------------------------------------------------
// AMM chain, round 4: counted-vmcnt deep pipeline (5 buf, depth 3) + fused
// [Q | W0'] precompute + single conversion kernel. 10 dispatches total.
//   chain: conv -> C1 [q|betas2] -> W0 -> [Q|W0'] -> C2 z0(soft) ->
//          4x z=soft(z0 + dg*z + z@Qoff) -> final y
// All GEMMs NT fp16-MFMA f32-accum, 64x64 tile, BK=64, 512 thr (2x2x2 waves),
// XOR-swizzled LDS staging via global_load_lds(16B), 1 raw s_barrier/K-step,
// loads kept in flight across barriers (s_waitcnt vmcnt(6/4/2/0)).
// ---------------------------------------------------------------------------

typedef _Float16 f16x8 __attribute__((ext_vector_type(8)));
typedef _Float16 f16x4 __attribute__((ext_vector_type(4)));
typedef float f32x4 __attribute__((ext_vector_type(4)));

enum { EPI_H, EPI_QW, EPI_SPLIT, EPI_SOFT, EPI_ZQ, EPI_FINAL };

typedef const __attribute__((address_space(1))) void* gas_ptr;
typedef __attribute__((address_space(3))) void* las_ptr;

__device__ __forceinline__ void gload16(const void* g, void* l) {
  __builtin_amdgcn_global_load_lds((gas_ptr)g, (las_ptr)l, 16, 0, 0);
}

__device__ __forceinline__ float softt(float t) {
  float s = fabsf(t) - 1.0f;
  s = s > 0.0f ? s : 0.0f;
  return copysignf(s, t);
}

// ---------------------------------------------------------------------------
// unified conversion kernel. block (32,8). z=0..3: transposing f32->f16 with
// optional scale; z=4: plain f32->f16 over 3 tensors (grid-stride).
// ---------------------------------------------------------------------------
__global__ __launch_bounds__(256) void convAll(
    const float* __restrict__ e0, const float* __restrict__ e1,
    const float* __restrict__ e2, const float* __restrict__ e3,
    _Float16* __restrict__ o0, _Float16* __restrict__ o1,
    _Float16* __restrict__ o2, _Float16* __restrict__ o3,
    const float* __restrict__ s1, const float* __restrict__ s2,
    const float4* __restrict__ pa, f16x4* __restrict__ qa, int na,
    const float4* __restrict__ pb, f16x4* __restrict__ qb, int nb,
    const float4* __restrict__ pc, f16x4* __restrict__ qc, int nc) {
  const int z = blockIdx.z;
  if (z == 4) {  // plain conversions
    const int total = na + nb + nc;
    const int bid = blockIdx.y * 32 + blockIdx.x;
    const int nthr = 2048 * 256;
    for (int i = bid * 256 + threadIdx.y * 32 + threadIdx.x; i < total;
         i += nthr) {
      const float4* s;
      f16x4* d;
      int j = i;
      if (j < na) {
        s = pa; d = qa;
      } else if ((j -= na) < nb) {
        s = pb; d = qb;
      } else {
        j -= nb; s = pc; d = qc;
      }
      float4 v = s[j];
      f16x4 h = {(_Float16)v.x, (_Float16)v.y, (_Float16)v.z, (_Float16)v.w};
      d[j] = h;
    }
    return;
  }
  const float* in = z == 0 ? e0 : z == 1 ? e1 : z == 2 ? e2 : e3;
  _Float16* out = z == 0 ? o0 : z == 1 ? o1 : z == 2 ? o2 : o3;
  const int R = (z < 2) ? 2048 : 1024;
  const int C = 1024;
  const int mode = z == 1 ? 1 : z == 2 ? 2 : 0;
  const float* sv = z == 1 ? s1 : s2;
  __shared__ float t[32][33];
  const int tx = threadIdx.x, ty = threadIdx.y;
  const int c0 = blockIdx.x * 32, r0 = blockIdx.y * 32;
  if (r0 >= R) return;  // uniform per block
#pragma unroll
  for (int i = 0; i < 32; i += 8)
    t[ty + i][tx] = in[(size_t)(r0 + ty + i) * C + c0 + tx];
  __syncthreads();
#pragma unroll
  for (int i = 0; i < 32; i += 8) {
    float v = t[tx][ty + i];
    if (mode == 1) v *= sv[c0 + ty + i];
    if (mode == 2) v *= sv[r0 + tx];
    out[(size_t)(c0 + ty + i) * R + r0 + tx] = (_Float16)v;
  }
}

// ---------------------------------------------------------------------------
// NT GEMM: C[m,n] = sum_k A[m,k]*B[n,k], fp16 in, f32 accum.
// 64x64 tile, BK=64, 512 thr = 8 waves in 2x2x2 (M x N x Ksplit), wave tile
// 32x32 (2x2 frags of 16x16x32 MFMA). 5-buffer LDS pipeline, stage depth 3,
// counted vmcnt (never 0 in steady state), one raw s_barrier per K-step.
// LDS swizzle: row r, chunk c (8 halfs) at r*64 + ((c ^ (r&7))*8).
// Safety: reuse distance 5 >= depth+2; stage(kt+3) issued after barrier(kt-1)
// which happens-after all reads of that buffer (step kt-2).
// ---------------------------------------------------------------------------
template <int EPI>
__global__ __launch_bounds__(512) void gemmk(
    const _Float16* __restrict__ A, const _Float16* __restrict__ B,
    const int N, const int K, const float* caux, const float* caux2,
    const float* dgv, float* dgout, float* outf,
    _Float16* __restrict__ outh, _Float16* __restrict__ outh2) {
  __shared__ __align__(16) _Float16 sm[40960];  // A: 5x4096 | B: 5x4096
  const int tid = threadIdx.x;
  const int lane = tid & 63;
  const int w = tid >> 6;       // 0..7
  const int wr = (w >> 1) & 1;  // M half
  const int wc = w & 1;         // N half
  const int wk = w >> 2;        // K half within BK
  const int brow = blockIdx.y << 6;
  const int bcol = blockIdx.x << 6;

  const int srow = lane >> 3;
  const int scol = ((lane & 7) ^ srow) << 3;  // pre-swizzled source chunk
  const int a15 = lane & 15;
  const int hi = lane >> 4;
  const int l7 = lane & 7;

  const _Float16* apg = A + (size_t)(brow + (w << 3) + srow) * K + scol;
  const _Float16* bpg = B + (size_t)(bcol + (w << 3) + srow) * K + scol;
  const int ldst = w << 9;

  // fragment read offsets (buffer-relative, halfs); row&7 == lane&7 here
  int raddr[2], baddr[2];
#pragma unroll
  for (int mi = 0; mi < 2; ++mi) {
    int ra = (wr << 5) + (mi << 4) + a15;
    int ca = ((wk << 2) + hi) ^ l7;  // XOR-swizzle decode
    raddr[mi] = ra * 64 + (ca << 3);
  }
#pragma unroll
  for (int ni = 0; ni < 2; ++ni) {
    int rb = (wc << 5) + (ni << 4) + a15;
    int cb = ((wk << 2) + hi) ^ l7;
    baddr[ni] = rb * 64 + (cb << 3);
  }

  f32x4 acc[2][2] = {};
  const int nK = K >> 6;  // >= 16 for all our shapes

  // prologue: stage tiles 0..2
#pragma unroll
  for (int p = 0; p < 3; ++p) {
    gload16(apg + (p << 6), sm + p * 4096 + ldst);
    gload16(bpg + (p << 6), sm + 20480 + p * 4096 + ldst);
  }

  int bi = 0, bs = 3;
  for (int kt = 0; kt < nK; ++kt) {
    if (kt + 3 < nK) {  // stage tile kt+3 (issue-early, stays in flight)
      gload16(apg + ((size_t)(kt + 3) << 6), sm + bs * 4096 + ldst);
      gload16(bpg + ((size_t)(kt + 3) << 6), sm + 20480 + bs * 4096 + ldst);
    }
    const int rem = nK - 1 - kt;
    if (rem >= 3)
      asm volatile("s_waitcnt vmcnt(6)" ::: "memory");
    else if (rem == 2)
      asm volatile("s_waitcnt vmcnt(4)" ::: "memory");
    else if (rem == 1)
      asm volatile("s_waitcnt vmcnt(2)" ::: "memory");
    else
      asm volatile("s_waitcnt vmcnt(0)" ::: "memory");
    __builtin_amdgcn_s_barrier();
    __builtin_amdgcn_sched_barrier(0);
    const _Float16* Ab = sm + bi * 4096;
    const _Float16* Bb = sm + 20480 + bi * 4096;
    f16x8 av[2], bv[2];
    av[0] = *(const f16x8*)(Ab + raddr[0]);
    av[1] = *(const f16x8*)(Ab + raddr[1]);
    bv[0] = *(const f16x8*)(Bb + baddr[0]);
    bv[1] = *(const f16x8*)(Bb + baddr[1]);
#pragma unroll
    for (int mi = 0; mi < 2; ++mi)
#pragma unroll
      for (int ni = 0; ni < 2; ++ni)
        acc[mi][ni] = __builtin_amdgcn_mfma_f32_16x16x32_f16(
            av[mi], bv[ni], acc[mi][ni], 0, 0, 0);
    bi = bi == 4 ? 0 : bi + 1;
    bs = bs == 4 ? 0 : bs + 1;
  }
  __syncthreads();  // all reads done before LDS reuse as f32 scratch

  // cross-K reduction through LDS scratch (16 KB)
  float* scr = (float*)sm;
  const int rbase = ((w & 3) * 64 + lane) * 16;
  if (wk == 1) {
#pragma unroll
    for (int mi = 0; mi < 2; ++mi)
#pragma unroll
      for (int ni = 0; ni < 2; ++ni)
        *(f32x4*)(scr + rbase + ((mi * 2 + ni) << 2)) = acc[mi][ni];
  }
  __syncthreads();
  if (wk == 1) return;
#pragma unroll
  for (int mi = 0; mi < 2; ++mi)
#pragma unroll
    for (int ni = 0; ni < 2; ++ni)
      acc[mi][ni] += *(const f32x4*)(scr + rbase + ((mi * 2 + ni) << 2));

  // epilogue: D layout col = lane&15, row = (lane>>4)*4 + r  [m89-verified]
#pragma unroll
  for (int mi = 0; mi < 2; ++mi) {
#pragma unroll
    for (int ni = 0; ni < 2; ++ni) {
#pragma unroll
      for (int r = 0; r < 4; ++r) {
        const int row = brow + (wr << 5) + (mi << 4) + (hi << 2) + r;
        const int col = bcol + (wc << 5) + (ni << 4) + a15;
        const float v = acc[mi][ni][r];
        const size_t idx = (size_t)row * N + col;
        if constexpr (EPI == EPI_H) {
          outh[idx] = (_Float16)v;
        } else if constexpr (EPI == EPI_QW) {
          // cols < 2048: Q = I - Ve Ve^T (off-diag f16, diag exact f32)
          // cols >= 2048: W0'^T = Ve @ W0^T
          if (col < 2048) {
            if (row == col) {
              dgout[row] = 1.0f - v;
              outh[(size_t)row * 2048 + col] = (_Float16)0.0f;
            } else {
              outh[(size_t)row * 2048 + col] = (_Float16)(-v);
            }
          } else {
            outh2[(size_t)row * 1024 + (col - 2048)] = (_Float16)v;
          }
        } else if constexpr (EPI == EPI_SPLIT) {
          if (col < 1024)
            outh[(size_t)row * 1024 + col] = (_Float16)v;
          else
            outh2[(size_t)row * 1024 + (col - 1024)] = (_Float16)v;
        } else if constexpr (EPI == EPI_SOFT) {
          outf[idx] = v;  // z0 (f32, feeds all ZQ epilogues)
          float s = softt(v);
          caux[0]; (void)0;  // (unused slot keeps signature uniform)
          ((float*)caux2)[idx] = s;  // z1 f32
          outh[idx] = (_Float16)s;
        } else if constexpr (EPI == EPI_ZQ) {
          // z_new = soft(z0 + dg[col]*z_prev + z_prev@Qoff, 1)
          float t = caux[idx] + dgv[col] * caux2[idx] + v;
          float s = softt(t);
          outf[idx] = s;  // aliases caux2 (same-thread read-before-write)
          outh[idx] = (_Float16)s;
        } else {  // EPI_FINAL: y = z + betas2@V1^T -> f32 d_out
          outf[idx] = caux[idx] + v;
        }
      }
    }
  }
}

// ---------------------------------------------------------------------------
extern "C" void kernel_launch(void* const* d_in, const int* in_sizes, int n_in,
                              void* d_out, int out_size, void* d_ws,
                              size_t ws_size, hipStream_t stream) {
  const float* x = (const float*)d_in[0];          // (512,2048)
  const float* key_enc = (const float*)d_in[1];    // (2048,1024)
  const float* val_enc = (const float*)d_in[2];    // (2048,1024)
  const float* keys_t0 = (const float*)d_in[3];    // (1024,1024)
  const float* vals_t0 = (const float*)d_in[4];    // (1024,1024)
  const float* scales_t0 = (const float*)d_in[5];  // (1024,)
  const float* keys_t1 = (const float*)d_in[6];    // (2048,1024)
  const float* vals_t1 = (const float*)d_in[7];    // (2048,1024)
  const float* scales_t1 = (const float*)d_in[8];  // (1024,)

  // workspace carve-up (~38 MB), lifetime-overlaid
  _Float16* wsh = (_Float16*)d_ws;
  _Float16* ve_h = wsh;                     // 2,097,152 (val_enc f16)
  _Float16* w0_h = wsh + 2097152;           // 1,048,576 (W0) -- contiguous
  //   => [ve_h ; w0_h] is the 3072x1024 B of the fused QW GEMM
  _Float16* vt1_h = wsh + 3145728;          // 2,097,152 (vals_t1 f16)
  _Float16* w0pT = wsh + 5242880;           // 2,097,152 (W0'^T = Ve@W0^T)
  _Float16* Bcat = wsh + 7340032;           // 4,194,304 [Ke^T ; K1^T*s1]
  _Float16* qoff = Bcat;                    //   overlay: Q off-diag (post C1)
  _Float16* x_h = wsh + 11534336;           // 1,048,576
  float* dg = (float*)x_h;                  //   overlay: Q diag (post C1)
  _Float16* kt0s = wsh + 12582912;          // 1,048,576 (K0^T * s0)
  _Float16* zh_A = kt0s;                    //   overlay after W0
  _Float16* vt0T = wsh + 13631488;          // 1,048,576 (vals_t0^T)
  _Float16* zh_B = vt0T;                    //   overlay after W0
  _Float16* q_h = wsh + 14680064;           // 524,288
  _Float16* be2_h = wsh + 15204352;         // 524,288
  float* z0_f = (float*)(wsh + 15728640);   // 512*2048 f32
  float* z_f = z0_f + 1048576;              // 512*2048 f32

  // 1) all conversions in one kernel
  convAll<<<dim3(32, 64, 5), dim3(32, 8), 0, stream>>>(
      key_enc, keys_t1, keys_t0, vals_t0, Bcat, Bcat + 2097152, kt0s, vt0T,
      scales_t1, scales_t0, (const float4*)x, (f16x4*)x_h, 262144,
      (const float4*)val_enc, (f16x4*)ve_h, 524288, (const float4*)vals_t1,
      (f16x4*)vt1_h, 524288);

  // 2) C1: [q | betas2] = x @ [Ke^T ; K1^T*s1] : M=512 N=2048 K=2048
  gemmk<EPI_SPLIT><<<dim3(32, 8), 512, 0, stream>>>(
      x_h, Bcat, 2048, 2048, nullptr, nullptr, nullptr, nullptr, nullptr, q_h,
      be2_h);
  // 3) W0 = (K0^T s0) @ V0 : M=1024 N=1024 K=1024
  gemmk<EPI_H><<<dim3(16, 16), 512, 0, stream>>>(
      kt0s, vt0T, 1024, 1024, nullptr, nullptr, nullptr, nullptr, nullptr,
      w0_h, nullptr);
  // 4) [Q | W0'^T] = Ve @ [Ve ; W0]^T : M=2048 N=3072 K=1024, grid 1536
  gemmk<EPI_QW><<<dim3(48, 32), 512, 0, stream>>>(
      ve_h, ve_h, 3072, 1024, nullptr, nullptr, nullptr, dg, nullptr, qoff,
      w0pT);
  // 5) C2: z0 = q @ W0' (soft fused -> z1) : M=512 N=2048 K=1024
  gemmk<EPI_SOFT><<<dim3(32, 8), 512, 0, stream>>>(
      q_h, w0pT, 2048, 1024, nullptr, (const float*)z_f, nullptr, nullptr,
      z0_f, zh_A, nullptr);
  // 6-9) ISTA iters 2..5: z = soft(z0 + dg*z + z@Qoff) : M=512 N=2048 K=2048
  gemmk<EPI_ZQ><<<dim3(32, 8), 512, 0, stream>>>(
      zh_A, qoff, 2048, 2048, z0_f, z_f, dg, nullptr, z_f, zh_B, nullptr);
  gemmk<EPI_ZQ><<<dim3(32, 8), 512, 0, stream>>>(
      zh_B, qoff, 2048, 2048, z0_f, z_f, dg, nullptr, z_f, zh_A, nullptr);
  gemmk<EPI_ZQ><<<dim3(32, 8), 512, 0, stream>>>(
      zh_A, qoff, 2048, 2048, z0_f, z_f, dg, nullptr, z_f, zh_B, nullptr);
  gemmk<EPI_ZQ><<<dim3(32, 8), 512, 0, stream>>>(
      zh_B, qoff, 2048, 2048, z0_f, z_f, dg, nullptr, z_f, zh_A, nullptr);
  // 10) final: y = z + betas2 @ V1^T : M=512 N=2048 K=1024 -> f32 d_out
  gemmk<EPI_FINAL><<<dim3(32, 8), 512, 0, stream>>>(
      be2_h, vt1_h, 2048, 1024, z_f, nullptr, nullptr, nullptr, (float*)d_out,
      nullptr, nullptr);
}